// Round 4
// baseline (116.869 us; speedup 1.0000x reference)
//
#include <hip/hip_runtime.h>

// RandomAttention: B=2, S=2048, NH=8, H=64, NKEYS=64, fp32.
// One wave per (b, q, head); lane = (g = key group, c = float4 chunk).
// R3 = R2 with the in-row byte offset FIXED: row (s,e) starts at
// s*2048 + e*256 bytes; per-lane chunk adds c*16. (R2 used e*2048 ->
// OOB reads -> memory fault.)
//  - readfirstlane(wave id) -> bases/offsets in SGPRs; K and V share
//    one 23-bit byte voffset (vi<<11 | e*256 | c*16).
//  - V rows prefetched into registers during phase 1 (vv[16]).
//  - softmax without max-subtraction (|score| small, exp2-safe fp32);
//    0.125*log2(e) folded into q; single normalization at the end.

#define BB 2
#define SS 2048
#define NHH 8
#define HH 64
#define NKEYS 64

__global__ __launch_bounds__(256, 4) void rand_attn_kernel(
    const float* __restrict__ q, const float* __restrict__ k,
    const float* __restrict__ v, const int* __restrict__ idx,
    float* __restrict__ out) {
  const int tid = threadIdx.x;
  const int lane = tid & 63;
  const int g = lane >> 4;   // key group 0..3 (key n == 4*j + g)
  const int c = lane & 15;   // float4 chunk within the 64-float row

  // Wave-uniform scalars in SGPRs.
  const int w = __builtin_amdgcn_readfirstlane(blockIdx.x * 4 + (tid >> 6));
  const int e = w & (NHH - 1);           // head
  const int bq = w >> 3;                 // b*S + s
  const int b = bq >> 11;                // S = 2048

  const float* kb = k + ((size_t)b * (SS * NHH * HH));
  const float* vb = v + ((size_t)b * (SS * NHH * HH));

  // Per-lane byte offset inside a gathered row: head slice + chunk.
  // Row (s,e) is at s*2048 + e*256 bytes; chunk c adds c*16.
  const int sco = e * (HH * 4) + c * 16;  // e*256 + c*16

  // q chunk, pre-scaled by H^-0.5 * log2(e) so scores are exp2-ready.
  float4 q4 = ((const float4*)(q + ((size_t)bq * NHH + e) * HH))[c];
  const float qs = 0.125f * 1.44269504f;
  q4.x *= qs; q4.y *= qs; q4.z *= qs; q4.w *= qs;

  // Lane n holds idx[bq, n].
  const int myidx = idx[bq * NKEYS + lane];

  float4 vv[16];  // prefetched V rows (this group's keys)
  float sc[16];   // log2-domain scores (replicated within group)

  // Phase 1: K gather + scores; V gather issued alongside (same voff).
#pragma unroll
  for (int j = 0; j < 16; ++j) {
    const int n = 4 * j + g;
    const int vi = __builtin_amdgcn_ds_bpermute(n << 2, myidx);
    const int voff = (vi << 11) + sco;   // byte offset < 2^23
    const float4 kv = *(const float4*)((const char*)kb + voff);
    vv[j] = *(const float4*)((const char*)vb + voff);
    float t = kv.x * q4.x + kv.y * q4.y + kv.z * q4.z + kv.w * q4.w;
    t += __shfl_xor(t, 1, 64);   // intra-group 16-lane reduce
    t += __shfl_xor(t, 2, 64);
    t += __shfl_xor(t, 4, 64);
    t += __shfl_xor(t, 8, 64);
    sc[j] = t;
  }

  // exp2 scores (no max subtraction), full-64-key normalization sum.
  float ssum = 0.f;
#pragma unroll
  for (int j = 0; j < 16; ++j) {
    sc[j] = __builtin_amdgcn_exp2f(sc[j]);
    ssum += sc[j];
  }
  ssum += __shfl_xor(ssum, 16, 64);
  ssum += __shfl_xor(ssum, 32, 64);
  const float inv = 1.0f / ssum;

  // Phase 2: pure register FMA against prefetched V.
  float4 acc = make_float4(0.f, 0.f, 0.f, 0.f);
#pragma unroll
  for (int j = 0; j < 16; ++j) {
    acc.x += sc[j] * vv[j].x;
    acc.y += sc[j] * vv[j].y;
    acc.z += sc[j] * vv[j].z;
    acc.w += sc[j] * vv[j].w;
  }
  // Cross-group sum, then normalize once.
  acc.x += __shfl_xor(acc.x, 16, 64);
  acc.y += __shfl_xor(acc.y, 16, 64);
  acc.z += __shfl_xor(acc.z, 16, 64);
  acc.w += __shfl_xor(acc.w, 16, 64);
  acc.x += __shfl_xor(acc.x, 32, 64);
  acc.y += __shfl_xor(acc.y, 32, 64);
  acc.z += __shfl_xor(acc.z, 32, 64);
  acc.w += __shfl_xor(acc.w, 32, 64);
  acc.x *= inv; acc.y *= inv; acc.z *= inv; acc.w *= inv;

  if (g == 0) {
    *(float4*)((char*)(out + (size_t)w * HH) + c * 16) = acc;
  }
}

extern "C" void kernel_launch(void* const* d_in, const int* in_sizes, int n_in,
                              void* d_out, int out_size, void* d_ws,
                              size_t ws_size, hipStream_t stream) {
  const float* q = (const float*)d_in[0];
  const float* k = (const float*)d_in[1];
  const float* v = (const float*)d_in[2];
  const int* idx = (const int*)d_in[3];
  float* out = (float*)d_out;

  // B*S*NH = 32768 waves; 4 waves per 256-thread block -> 8192 blocks.
  const int n_blocks = (BB * SS * NHH) / 4;
  rand_attn_kernel<<<n_blocks, 256, 0, stream>>>(q, k, v, idx, out);
}